// Round 2
// baseline (496.802 us; speedup 1.0000x reference)
//
#include <hip/hip_runtime.h>

// S5 forward: GEMM1 (u @ Bbar^T) -> chunked complex scan -> GEMM2 (xs @ C'^T) + D*u
// B=8, L=4096, H=1024, P=512.  M = B*L = 32768, K = 1024, N = 1024 for both GEMMs.

#define Bsz 8
#define Lseq 4096
#define Hdim 1024
#define Pdim 512
#define NCHUNK 64
#define CHUNK 64
#define MROWS 32768

typedef __attribute__((ext_vector_type(8))) __bf16 bf16x8;
typedef __attribute__((ext_vector_type(4))) float f32x4;

__device__ __forceinline__ unsigned short f2bf(float f) {
  union { float f; unsigned u; } v; v.f = f;
  unsigned r = v.u + 0x7fffu + ((v.u >> 16) & 1u);
  return (unsigned short)(r >> 16);
}
__device__ __forceinline__ float bf2f(unsigned short s) {
  union { unsigned u; float f; } v; v.u = ((unsigned)s) << 16;
  return v.f;
}

__device__ __forceinline__ void gld_lds16(const void* g, void* l) {
  __builtin_amdgcn_global_load_lds(
      (const __attribute__((address_space(1))) unsigned int*)g,
      (__attribute__((address_space(3))) unsigned int*)l, 16, 0, 0);
}

// ---------------- setup: a = exp(Lambda*step), aS = a^CHUNK, g = (a-1)/Lambda ----------
__global__ void k_setup(const float* __restrict__ Lre_in, const float* __restrict__ Lim_in,
                        const float* __restrict__ log_step,
                        float2* __restrict__ a_arr, float2* __restrict__ aS_arr,
                        float2* __restrict__ g_arr) {
  int p = threadIdx.x;
  if (p >= Pdim) return;
  float lre = fminf(Lre_in[p], -1e-4f);
  float lim = Lim_in[p];
  float step = expf(log_step[p]);
  float zr = lre * step, zi = lim * step;
  float er = expf(zr);
  float ar = er * cosf(zi), ai = er * sinf(zi);
  a_arr[p] = make_float2(ar, ai);
  float erS = expf(zr * (float)CHUNK);
  aS_arr[p] = make_float2(erS * cosf(zi * (float)CHUNK), erS * sinf(zi * (float)CHUNK));
  float den = lre * lre + lim * lim;
  float nr = ar - 1.0f, ni = ai;
  g_arr[p] = make_float2((nr * lre + ni * lim) / den, (ni * lre - nr * lim) / den);
}

// ---------------- prep Bbar' (N=2P rows, K=H) bf16 ----------------
__global__ void k_prep_B(const float* __restrict__ Bin, const float2* __restrict__ g_arr,
                         unsigned short* __restrict__ Bbar2) {
  int idx = blockIdx.x * 256 + threadIdx.x;   // over P*H = 524288
  int p = idx >> 10;
  int h = idx & 1023;
  float B0 = Bin[2 * idx];      // B[p,h,0] : p*H*2 + h*2
  float B1 = Bin[2 * idx + 1];
  float2 g = g_arr[p];
  Bbar2[(size_t)p * Hdim + h]            = f2bf(g.x * B0 - g.y * B1);
  Bbar2[(size_t)(Pdim + p) * Hdim + h]   = f2bf(g.x * B1 + g.y * B0);
}

// ---------------- prep C' (N=H rows, K=2P) bf16 : [C_re | -C_im] ----------------
__global__ void k_prep_C(const float* __restrict__ Cin, unsigned short* __restrict__ C2m) {
  int idx = blockIdx.x * 256 + threadIdx.x;   // over H*P = 524288
  int h = idx >> 9;
  int p = idx & 511;
  float C0 = Cin[2 * idx];      // C[h,p,0] : h*P*2 + p*2
  float C1 = Cin[2 * idx + 1];
  C2m[(size_t)h * 1024 + p]        = f2bf(C0);
  C2m[(size_t)h * 1024 + 512 + p]  = f2bf(-C1);
}

// ---------------- u fp32 -> bf16 ----------------
__global__ void k_cvt_u(const float* __restrict__ u, unsigned short* __restrict__ ub) {
  size_t i = ((size_t)blockIdx.x * 256 + threadIdx.x) * 4;
  float4 v = *(const float4*)(u + i);
  ushort4 o;
  o.x = f2bf(v.x); o.y = f2bf(v.y); o.z = f2bf(v.z); o.w = f2bf(v.w);
  *(ushort4*)(ub + i) = o;
}

// ---------------- bf16 GEMM, B^T input, double-buffered LDS pipeline ----------------
// C[m,n] = sum_k A[m,k] * Bt[n,k];  M = 32768, N = 1024, K = 1024.
// Grid: 2048 1-D.  XCD-aware mapping: n-tile = wg & 7, m-tile = wg >> 3.
// Each XCD pinned to one n-tile (B L2-resident); 8 XCDs sweep same m in near-lockstep
// (A fetched from HBM once, served to the other 7 XCDs from L3).
// 5 blocks/CU (LDS 32KB x 5 = 160KB exactly) for latency hiding across the per-iter
// barrier drain.
// LDS swizzle: slot (row r, chunk c) holds global k-chunk c ^ ((r>>1)&3); read back
// with c = quad ^ ((mrow>>1)&3) (invariant across mt/nt -> hoisted).
// EPI 0: bf16 store via LDS transpose (256B runs).  EPI 1: fp32 = acc + D[n]*u[m,n].
template <int EPI>
__global__ __launch_bounds__(256, 5) void gemm_bt(const unsigned short* __restrict__ A,
                                                  const unsigned short* __restrict__ Bt,
                                                  void* __restrict__ Cout,
                                                  const float* __restrict__ uin,
                                                  const float* __restrict__ Dvec) {
  const int K = 1024;
  __shared__ __align__(16) unsigned short sm[16384];
  char* smc = (char*)sm;

  int tid = threadIdx.x;
  int lane = tid & 63;
  int w = tid >> 6;          // wave 0..3
  int wr = w >> 1, wc = w & 1;
  int quad = lane >> 4;      // 0..3
  int mrow = lane & 15;

  int wg = blockIdx.x;
  size_t rowBase = (size_t)(wg >> 3) * 128;   // m-tile
  size_t colBase = (size_t)(wg & 7) * 128;    // n-tile (pinned per XCD)

  f32x4 acc[4][4];
#pragma unroll
  for (int i = 0; i < 4; i++)
#pragma unroll
    for (int j = 0; j < 4; j++) acc[i][j] = (f32x4){0.f, 0.f, 0.f, 0.f};

  // staging addresses (loop-invariant): slot idx = j*256 + tid; r = idx>>2; c = (idx&3)^((idx>>3)&3)
  int r0 = tid >> 2;
  int cst = (tid & 3) ^ ((tid >> 3) & 3);
  const unsigned short* pa0 = A + rowBase * K + (size_t)r0 * K + cst * 8;
  const unsigned short* pa1 = pa0 + (size_t)64 * K;
  const unsigned short* pb0 = Bt + colBase * K + (size_t)r0 * K + cst * 8;
  const unsigned short* pb1 = pb0 + (size_t)64 * K;
  int dA0 = w * 1024, dA1 = 4096 + w * 1024;
  int dB0 = 8192 + w * 1024, dB1 = 12288 + w * 1024;

  // LDS read bases (shorts), loop-invariant; frag mt/nt at +mt*512 shorts
  int cr = quad ^ ((mrow >> 1) & 3);
  int aOff = (wr * 64 + mrow) * 32 + cr * 8;
  int bOff = 4096 + (wc * 64 + mrow) * 32 + cr * 8;

  // prologue: stage tile 0 into buf 0
  gld_lds16(pa0, smc + dA0);
  gld_lds16(pa1, smc + dA1);
  gld_lds16(pb0, smc + dB0);
  gld_lds16(pb1, smc + dB1);

  for (int i = 0; i < 32; ++i) {
    __syncthreads();                       // drains vmcnt -> tile i resident; buf[i^1] free
    int cur = i & 1;
    if (i < 31) {
      int kb = (i + 1) * 32;
      int bb = (cur ^ 1) * 16384;
      gld_lds16(pa0 + kb, smc + bb + dA0);
      gld_lds16(pa1 + kb, smc + bb + dA1);
      gld_lds16(pb0 + kb, smc + bb + dB0);
      gld_lds16(pb1 + kb, smc + bb + dB1);
    }
    const unsigned short* Ab = sm + cur * 8192 + aOff;
    const unsigned short* Bb = sm + cur * 8192 + bOff;
    bf16x8 af[4], bfv[4];
#pragma unroll
    for (int mt = 0; mt < 4; mt++) af[mt] = *(const bf16x8*)(Ab + mt * 512);
#pragma unroll
    for (int nt = 0; nt < 4; nt++) bfv[nt] = *(const bf16x8*)(Bb + nt * 512);
#pragma unroll
    for (int mt = 0; mt < 4; mt++)
#pragma unroll
      for (int nt = 0; nt < 4; nt++)
        acc[mt][nt] = __builtin_amdgcn_mfma_f32_16x16x32_bf16(af[mt], bfv[nt], acc[mt][nt], 0, 0, 0);
  }

  // epilogue: C/D layout col = lane&15, row = quad*4 + r
  if (EPI == 0) {
    // LDS-transposed bf16 store: 2 passes of 64 rows through sm (stride 136)
    unsigned short* O = (unsigned short*)Cout;
    __syncthreads();
#pragma unroll
    for (int ph = 0; ph < 2; ph++) {
      if (wr == ph) {
#pragma unroll
        for (int mt = 0; mt < 4; mt++)
#pragma unroll
          for (int nt = 0; nt < 4; nt++)
#pragma unroll
            for (int r = 0; r < 4; r++) {
              int lr = mt * 16 + quad * 4 + r;
              int col = wc * 64 + nt * 16 + mrow;
              sm[lr * 136 + col] = f2bf(acc[mt][nt][r]);
            }
      }
      __syncthreads();
#pragma unroll
      for (int it = 0; it < 4; it++) {
        int cid = it * 256 + tid;           // 0..1023 over 64 rows x 16 chunks
        int lr = cid >> 4;
        int cc = cid & 15;
        uint4 v = *(const uint4*)(sm + lr * 136 + cc * 8);
        *(uint4*)(O + (rowBase + ph * 64 + lr) * 1024 + colBase + cc * 8) = v;
      }
      __syncthreads();
    }
  } else {
    float* O = (float*)Cout;
    size_t mBase = rowBase + wr * 64 + quad * 4;
    size_t nBase = colBase + wc * 64 + mrow;
#pragma unroll
    for (int mt = 0; mt < 4; mt++)
#pragma unroll
      for (int nt = 0; nt < 4; nt++) {
        size_t n = nBase + nt * 16;
        float dv = Dvec[n];
#pragma unroll
        for (int r = 0; r < 4; r++) {
          size_t m = mBase + mt * 16 + r;
          O[m * 1024 + n] = acc[mt][nt][r] + dv * uin[m * 1024 + n];
        }
      }
  }
}

// ---------------- scan phase 1: per-chunk aggregate T_c ----------------
// 1 chunk per 256-thread block (512 blocks, 2 blocks/CU), 2 p-states/thread (4B loads).
__global__ void k_scan1(const unsigned short* __restrict__ Bu, const float2* __restrict__ a_arr,
                        float* __restrict__ carryT) {
  int bc = blockIdx.x;                       // b*NCHUNK + c, 0..511
  int p0 = threadIdx.x * 2;                  // 0,2,..,510
  int b = bc >> 6, c = bc & 63;
  float2 a0 = a_arr[p0], a1 = a_arr[p0 + 1];
  const unsigned short* bu = Bu + ((size_t)b * Lseq + (size_t)c * CHUNK) * 1024;
  float tr0 = 0.f, ti0 = 0.f, tr1 = 0.f, ti1 = 0.f;
#pragma unroll 8
  for (int l = 0; l < CHUNK; l++) {
    unsigned vr = *(const unsigned*)(bu + (size_t)l * 1024 + p0);
    unsigned vi = *(const unsigned*)(bu + (size_t)l * 1024 + 512 + p0);
    float br0 = bf2f((unsigned short)vr), br1 = bf2f((unsigned short)(vr >> 16));
    float bi0 = bf2f((unsigned short)vi), bi1 = bf2f((unsigned short)(vi >> 16));
    float nr0 = fmaf(a0.x, tr0, fmaf(-a0.y, ti0, br0));
    ti0 = fmaf(a0.x, ti0, fmaf(a0.y, tr0, bi0));
    tr0 = nr0;
    float nr1 = fmaf(a1.x, tr1, fmaf(-a1.y, ti1, br1));
    ti1 = fmaf(a1.x, ti1, fmaf(a1.y, tr1, bi1));
    tr1 = nr1;
  }
  *(float2*)(carryT + (size_t)bc * 1024 + p0) = make_float2(tr0, tr1);
  *(float2*)(carryT + (size_t)bc * 1024 + 512 + p0) = make_float2(ti0, ti1);
}

// ---------------- scan phase 2: wave-parallel Kogge-Stone over chunk carries ----------
// One wave per (b,p): lane = chunk c. Inclusive KS with uniform multiplier s^d
// (repeated squaring), then shift to exclusive. 4096 waves = 1024 blocks.
__global__ void k_scan2(const float* __restrict__ carryT, const float2* __restrict__ aS_arr,
                        float* __restrict__ prefix) {
  int wid = blockIdx.x * 4 + (threadIdx.x >> 6);   // 0..4095
  int lane = threadIdx.x & 63;                     // chunk index c
  int b = wid >> 9;                                // 0..7
  int p = wid & 511;                               // 0..511
  float2 s = aS_arr[p];
  size_t o = ((size_t)(b * NCHUNK + lane)) * 1024 + p;
  float tr = carryT[o], ti = carryT[o + 512];
  // inclusive scan: S_c = sum_{j<=c} s^(c-j) T_j
  float mr = s.x, mi = s.y;                        // s^d, starting d=1
#pragma unroll
  for (int d = 1; d < 64; d <<= 1) {
    float ur = __shfl_up(tr, d, 64);
    float ui = __shfl_up(ti, d, 64);
    if (lane >= d) {
      tr = fmaf(mr, ur, fmaf(-mi, ui, tr));
      ti = fmaf(mr, ui, fmaf(mi, ur, ti));
    }
    float nmr = mr * mr - mi * mi;                 // s^d -> s^(2d)
    mi = 2.f * mr * mi;
    mr = nmr;
  }
  // exclusive: prefix before chunk c = S_{c-1}; chunk 0 starts at 0
  float er = __shfl_up(tr, 1, 64);
  float ei = __shfl_up(ti, 1, 64);
  if (lane == 0) { er = 0.f; ei = 0.f; }
  prefix[o] = er;
  prefix[o + 512] = ei;
}

// ---------------- scan phase 3: replay chunk from carry-in, write xs bf16 ----------
// 1 chunk per 256-thread block (512 blocks), 2 p-states/thread.
__global__ void k_scan3(const unsigned short* __restrict__ Bu, const float2* __restrict__ a_arr,
                        const float* __restrict__ prefix, unsigned short* __restrict__ xs) {
  int bc = blockIdx.x;
  int p0 = threadIdx.x * 2;
  int b = bc >> 6, c = bc & 63;
  float2 a0 = a_arr[p0], a1 = a_arr[p0 + 1];
  size_t base = ((size_t)b * Lseq + (size_t)c * CHUNK) * 1024;
  size_t po = (size_t)bc * 1024 + p0;
  float2 xrv = *(const float2*)(prefix + po);
  float2 xiv = *(const float2*)(prefix + po + 512);
  float xr0 = xrv.x, xr1 = xrv.y, xi0 = xiv.x, xi1 = xiv.y;
#pragma unroll 8
  for (int l = 0; l < CHUNK; l++) {
    unsigned vr = *(const unsigned*)(Bu + base + (size_t)l * 1024 + p0);
    unsigned vi = *(const unsigned*)(Bu + base + (size_t)l * 1024 + 512 + p0);
    float br0 = bf2f((unsigned short)vr), br1 = bf2f((unsigned short)(vr >> 16));
    float bi0 = bf2f((unsigned short)vi), bi1 = bf2f((unsigned short)(vi >> 16));
    float nr0 = fmaf(a0.x, xr0, fmaf(-a0.y, xi0, br0));
    xi0 = fmaf(a0.x, xi0, fmaf(a0.y, xr0, bi0));
    xr0 = nr0;
    float nr1 = fmaf(a1.x, xr1, fmaf(-a1.y, xi1, br1));
    xi1 = fmaf(a1.x, xi1, fmaf(a1.y, xr1, bi1));
    xr1 = nr1;
    unsigned orv = (unsigned)f2bf(xr0) | ((unsigned)f2bf(xr1) << 16);
    unsigned oiv = (unsigned)f2bf(xi0) | ((unsigned)f2bf(xi1) << 16);
    *(unsigned*)(xs + base + (size_t)l * 1024 + p0) = orv;
    *(unsigned*)(xs + base + (size_t)l * 1024 + 512 + p0) = oiv;
  }
}

extern "C" void kernel_launch(void* const* d_in, const int* in_sizes, int n_in,
                              void* d_out, int out_size, void* d_ws, size_t ws_size,
                              hipStream_t stream) {
  const float* u     = (const float*)d_in[0];
  const float* Lre   = (const float*)d_in[1];
  const float* Lim   = (const float*)d_in[2];
  const float* Bin   = (const float*)d_in[3];
  const float* Cin   = (const float*)d_in[4];
  const float* Dvec  = (const float*)d_in[5];
  const float* lstep = (const float*)d_in[6];

  char* ws = (char*)d_ws;
  // ws layout (~75.5 MB):
  unsigned short* ubf_xs = (unsigned short*)(ws);                    // 67,108,864 B (u_bf16, later reused as xs)
  unsigned short* Bbar2  = (unsigned short*)(ws + 67108864);         // 2 MB
  unsigned short* C2m    = (unsigned short*)(ws + 69206016);         // 2 MB
  float*          carryT = (float*)(ws + 71303168);                  // 2 MB
  float*          prefix = (float*)(ws + 73400320);                  // 2 MB
  float2*         a_arr  = (float2*)(ws + 75497472);
  float2*         aS_arr = (float2*)(ws + 75501568);
  float2*         g_arr  = (float2*)(ws + 75505664);

  // Bu lives in d_out (bf16, 67MB of the 134MB out buffer); dead before GEMM2 writes out.
  unsigned short* Bu = (unsigned short*)d_out;

  k_setup<<<1, 512, 0, stream>>>(Lre, Lim, lstep, a_arr, aS_arr, g_arr);
  k_prep_B<<<2048, 256, 0, stream>>>(Bin, g_arr, Bbar2);
  k_prep_C<<<2048, 256, 0, stream>>>(Cin, C2m);
  k_cvt_u<<<32768, 256, 0, stream>>>(u, ubf_xs);

  gemm_bt<0><<<2048, 256, 0, stream>>>(ubf_xs, Bbar2, (void*)Bu, nullptr, nullptr);

  k_scan1<<<512, 256, 0, stream>>>(Bu, a_arr, carryT);
  k_scan2<<<1024, 256, 0, stream>>>(carryT, aS_arr, prefix);
  k_scan3<<<512, 256, 0, stream>>>(Bu, a_arr, prefix, ubf_xs);

  gemm_bt<1><<<2048, 256, 0, stream>>>(ubf_xs, C2m, d_out, u, Dvec);
}